// Round 11
// baseline (73.512 us; speedup 1.0000x reference)
//
#include <hip/hip_runtime.h>

#define D_MODEL 2048
#define NUM_TILES 64
#define D_SLICE 32
#define TILES_PER_CLUSTER 8
#define NUM_CLUSTERS 8
#define GRID_PTS 16
#define LN_EPS 1e-5f
#define NBUCKET 64

// native 4-float vector (works with __builtin_nontemporal_*)
typedef float f32x4 __attribute__((ext_vector_type(4)));

// order-preserving float<->uint map for atomic min/max
__device__ __forceinline__ unsigned int encF(float f) {
    unsigned int u = __float_as_uint(f);
    return (u & 0x80000000u) ? ~u : (u | 0x80000000u);
}
__device__ __forceinline__ float decF(unsigned int u) {
    unsigned int b = (u & 0x80000000u) ? (u ^ 0x80000000u) : ~u;
    return __uint_as_float(b);
}

// Kernel A: slope_sign per dim + init bucketed tile min/max (ws is poisoned).
__global__ void kan_setup(const float* __restrict__ slopes,
                          float* __restrict__ sgn,
                          unsigned int* __restrict__ tminb,
                          unsigned int* __restrict__ tmaxb) {
    int d = blockIdx.x * blockDim.x + threadIdx.x;  // 0..4095
    if (d < NUM_TILES * NBUCKET) { tminb[d] = 0xFFFFFFFFu; tmaxb[d] = 0u; }
    if (d < D_MODEL) {
        const float* p = slopes + (size_t)d * GRID_PTS;
        float s = 0.f;
#pragma unroll
        for (int k = 0; k < GRID_PTS; ++k) s += p[k];
        float m = s * (1.0f / GRID_PTS);
        sgn[d] = (m > 0.f) ? 1.f : ((m < 0.f) ? -1.f : 0.f);
    }
}

// Kernel B: TWO tokens per block (R4 structure, doubled). Both tokens' x
// loads issue up front (2x MLP, load latency of token B hidden under token
// A's compute); weights loaded once, reused; fused dual reduction shares one
// butterfly + one LDS round + one barrier; two serial argmaxes run on
// threads 0 and 1 concurrently. 4 barriers / 2 tokens.
__launch_bounds__(256)
__global__ void kan_main(const float* __restrict__ x,
                         const float* __restrict__ gamma,
                         const float* __restrict__ beta,
                         const float* __restrict__ sgn,
                         float* __restrict__ out,
                         float* __restrict__ xn_slice,
                         int* __restrict__ tidx_out,
                         unsigned int* __restrict__ tminb,
                         unsigned int* __restrict__ tmaxb) {
    const int nA = blockIdx.x * 2;
    const int nB = nA + 1;
    const int tid = threadIdx.x;
    const size_t baseA = (size_t)nA * D_MODEL + (size_t)tid * 8;
    const size_t baseB = (size_t)nB * D_MODEL + (size_t)tid * 8;

    // ---- both tokens' loads issued up front (16 outstanding 16B/thread-pair)
    f32x4 a  = *(const f32x4*)(x + baseA);
    f32x4 b  = *(const f32x4*)(x + baseA + 4);
    f32x4 a2 = *(const f32x4*)(x + baseB);
    f32x4 b2 = *(const f32x4*)(x + baseB + 4);

    // ---- out = x copies: nontemporal, issued early ----
    __builtin_nontemporal_store(a,  (f32x4*)(out + baseA));
    __builtin_nontemporal_store(b,  (f32x4*)(out + baseA + 4));
    __builtin_nontemporal_store(a2, (f32x4*)(out + baseB));
    __builtin_nontemporal_store(b2, (f32x4*)(out + baseB + 4));

    // ---- weights: loaded ONCE, reused for both tokens ----
    f32x4 g0 = *(const f32x4*)(gamma + tid * 8);
    f32x4 g1 = *(const f32x4*)(gamma + tid * 8 + 4);
    f32x4 b0 = *(const f32x4*)(beta + tid * 8);
    f32x4 b1 = *(const f32x4*)(beta + tid * 8 + 4);
    f32x4 sg0 = *(const f32x4*)(sgn + tid * 8);
    f32x4 sg1 = *(const f32x4*)(sgn + tid * 8 + 4);

    float xvA[8] = {a.x, a.y, a.z, a.w, b.x, b.y, b.z, b.w};
    float xvB[8] = {a2.x, a2.y, a2.z, a2.w, b2.x, b2.y, b2.z, b2.w};

    __shared__ f32x4 red[4];
    __shared__ int tsA[NUM_TILES];
    __shared__ int tsB[NUM_TILES];
    __shared__ int csA[NUM_CLUSTERS];
    __shared__ int csB[NUM_CLUSTERS];
    __shared__ int chosenA, chosenB;

    // ---- fused dual sum+sumsq: 4 values through one butterfly chain ----
    float sA = 0.f, qA = 0.f, sB = 0.f, qB = 0.f;
#pragma unroll
    for (int k = 0; k < 8; ++k) {
        sA += xvA[k]; qA += xvA[k] * xvA[k];
        sB += xvB[k]; qB += xvB[k] * xvB[k];
    }
#pragma unroll
    for (int off = 32; off > 0; off >>= 1) {
        sA += __shfl_xor(sA, off);
        qA += __shfl_xor(qA, off);
        sB += __shfl_xor(sB, off);
        qB += __shfl_xor(qB, off);
    }
    if ((tid & 63) == 0) red[tid >> 6] = f32x4{sA, qA, sB, qB};
    __syncthreads();  // barrier 1
    f32x4 R = red[0] + red[1] + red[2] + red[3];
    const float muA = R.x * (1.0f / D_MODEL);
    const float muB = R.z * (1.0f / D_MODEL);
    const float rsA = rsqrtf(fmaxf(R.y * (1.0f / D_MODEL) - muA * muA, 0.0f) + LN_EPS);
    const float rsB = rsqrtf(fmaxf(R.w * (1.0f / D_MODEL) - muB * muB, 0.0f) + LN_EPS);

    // ---- normalized values + integer sign scores, both tokens ----
    float gv[8] = {g0.x, g0.y, g0.z, g0.w, g1.x, g1.y, g1.z, g1.w};
    float bv[8] = {b0.x, b0.y, b0.z, b0.w, b1.x, b1.y, b1.z, b1.w};
    float sv[8] = {sg0.x, sg0.y, sg0.z, sg0.w, sg1.x, sg1.y, sg1.z, sg1.w};

    float xnA[8], xnB[8];
    int scA = 0, scB = 0;
#pragma unroll
    for (int k = 0; k < 8; ++k) {
        xnA[k] = (xvA[k] - muA) * rsA * gv[k] + bv[k];
        xnB[k] = (xvB[k] - muB) * rsB * gv[k] + bv[k];
        int s1A = (xnA[k] > 0.f) ? 1 : ((xnA[k] < 0.f) ? -1 : 0);
        int s1B = (xnB[k] > 0.f) ? 1 : ((xnB[k] < 0.f) ? -1 : 0);
        scA += s1A * (int)sv[k];
        scB += s1B * (int)sv[k];
    }
    scA += __shfl_xor(scA, 1);
    scA += __shfl_xor(scA, 2);
    scB += __shfl_xor(scB, 1);
    scB += __shfl_xor(scB, 2);
    if ((tid & 3) == 0) { tsA[tid >> 2] = scA; tsB[tid >> 2] = scB; }
    __syncthreads();  // barrier 2

    // ---- cluster sums: 16 threads (8 for A, 8 for B) ----
    if (tid < 2 * NUM_CLUSTERS) {
        const int* t_ = (tid < NUM_CLUSTERS) ? tsA : tsB;
        int c = tid & 7;
        int acc = 0;
#pragma unroll
        for (int t = 0; t < TILES_PER_CLUSTER; ++t) acc += t_[c * TILES_PER_CLUSTER + t];
        if (tid < NUM_CLUSTERS) csA[c] = acc; else csB[c] = acc;
    }
    __syncthreads();  // barrier 3

    // ---- serial argmaxes on threads 0 (A) and 1 (B), concurrent ----
    if (tid == 0) {
        int bc = 0, bv_ = -2147483647;
#pragma unroll
        for (int c = 0; c < NUM_CLUSTERS; ++c)
            if (csA[c] > bv_) { bv_ = csA[c]; bc = c; }
        int t0 = bc * TILES_PER_CLUSTER;
        int bt = t0, btv = tsA[t0];
#pragma unroll
        for (int t = 1; t < TILES_PER_CLUSTER; ++t)
            if (tsA[t0 + t] > btv) { btv = tsA[t0 + t]; bt = t0 + t; }
        chosenA = bt;
        tidx_out[nA] = bt;
    }
    if (tid == 1) {
        int bc = 0, bv_ = -2147483647;
#pragma unroll
        for (int c = 0; c < NUM_CLUSTERS; ++c)
            if (csB[c] > bv_) { bv_ = csB[c]; bc = c; }
        int t0 = bc * TILES_PER_CLUSTER;
        int bt = t0, btv = tsB[t0];
#pragma unroll
        for (int t = 1; t < TILES_PER_CLUSTER; ++t)
            if (tsB[t0 + t] > btv) { btv = tsB[t0 + t]; bt = t0 + t; }
        chosenB = bt;
        tidx_out[nB] = bt;
    }
    __syncthreads();  // barrier 4
    const int tileA = chosenA;
    const int tileB = chosenB;

    // ---- stash xn slices (4 threads each token, 128B contiguous) ----
    if ((tid >> 2) == tileA) {
        float* qp = xn_slice + (size_t)nA * D_SLICE + (tid & 3) * 8;
        *(f32x4*)(qp) = f32x4{xnA[0], xnA[1], xnA[2], xnA[3]};
        *(f32x4*)(qp + 4) = f32x4{xnA[4], xnA[5], xnA[6], xnA[7]};
    }
    if ((tid >> 2) == tileB) {
        float* qp = xn_slice + (size_t)nB * D_SLICE + (tid & 3) * 8;
        *(f32x4*)(qp) = f32x4{xnB[0], xnB[1], xnB[2], xnB[3]};
        *(f32x4*)(qp + 4) = f32x4{xnB[4], xnB[5], xnB[6], xnB[7]};
    }

    // ---- chosen-tile min/max -> bucketed atomics, both tokens ----
    float mnA = xnA[0], mxA = xnA[0], mnB = xnB[0], mxB = xnB[0];
#pragma unroll
    for (int k = 1; k < 8; ++k) {
        mnA = fminf(mnA, xnA[k]); mxA = fmaxf(mxA, xnA[k]);
        mnB = fminf(mnB, xnB[k]); mxB = fmaxf(mxB, xnB[k]);
    }
    mnA = fminf(mnA, __shfl_xor(mnA, 1)); mnA = fminf(mnA, __shfl_xor(mnA, 2));
    mxA = fmaxf(mxA, __shfl_xor(mxA, 1)); mxA = fmaxf(mxA, __shfl_xor(mxA, 2));
    mnB = fminf(mnB, __shfl_xor(mnB, 1)); mnB = fminf(mnB, __shfl_xor(mnB, 2));
    mxB = fmaxf(mxB, __shfl_xor(mxB, 1)); mxB = fmaxf(mxB, __shfl_xor(mxB, 2));
    if (tid == tileA * 4) {
        int bkt = nA & (NBUCKET - 1);
        atomicMin(&tminb[tileA * NBUCKET + bkt], encF(mnA));
        atomicMax(&tmaxb[tileA * NBUCKET + bkt], encF(mxA));
    }
    if (tid == tileB * 4) {
        int bkt = nB & (NBUCKET - 1);
        atomicMin(&tminb[tileB * NBUCKET + bkt], encF(mnB));
        atomicMax(&tmaxb[tileB * NBUCKET + bkt], encF(mxB));
    }
}

// Kernel B2: reduce 64 buckets -> final per-tile min/max. One block, 64 thr.
__global__ void kan_reduce(const unsigned int* __restrict__ tminb,
                           const unsigned int* __restrict__ tmaxb,
                           unsigned int* __restrict__ tmin,
                           unsigned int* __restrict__ tmax) {
    int t = threadIdx.x;  // 0..63
    unsigned int mn = 0xFFFFFFFFu, mx = 0u;
#pragma unroll 4
    for (int b = 0; b < NBUCKET; ++b) {
        mn = min(mn, tminb[t * NBUCKET + b]);
        mx = max(mx, tmaxb[t * NBUCKET + b]);
    }
    tmin[t] = mn;
    tmax[t] = mx;
}

// Kernel C: one thread per (token, quad). Spline delta, float4 RMW on out.
__global__ void kan_apply(const float* __restrict__ xn_slice,
                          const int* __restrict__ tidx,
                          const float* __restrict__ bases,
                          const float* __restrict__ slopes,
                          const float* __restrict__ oscale,
                          const unsigned int* __restrict__ tmin,
                          const unsigned int* __restrict__ tmax,
                          float* __restrict__ out, int N) {
    int g = blockIdx.x * blockDim.x + threadIdx.x;
    if (g >= N * 8) return;
    int n = g >> 3;
    int qd = g & 7;  // quad of 4 dims: j = 4*qd..4*qd+3
    int t = tidx[n];
    f32x4 xn4 = *(const f32x4*)(xn_slice + (size_t)n * D_SLICE + qd * 4);
    float mn = decF(tmin[t]);
    float mx = decF(tmax[t]);
    float inv = 1.0f / (mx - mn + 1e-8f);
    float osc = oscale[t];

    float dl[4];
    float xnv[4] = {xn4.x, xn4.y, xn4.z, xn4.w};
#pragma unroll
    for (int e = 0; e < 4; ++e) {
        float u = (xnv[e] - mn) * inv;
        u = fminf(fmaxf(u, 0.0f), 1.0f - 1e-6f);
        int gi = (int)(u * (float)GRID_PTS);
        gi = min(max(gi, 0), GRID_PTS - 1);
        int j = qd * 4 + e;
        int off = (t * D_SLICE + j) * GRID_PTS + gi;
        float xl = (u - (float)gi * (1.0f / GRID_PTS)) * (float)GRID_PTS;
        dl[e] = (bases[off] + slopes[off] * xl) * osc;
    }
    size_t oi = (size_t)n * D_MODEL + t * D_SLICE + qd * 4;
    f32x4 o = *(f32x4*)(out + oi);
    o.x += dl[0]; o.y += dl[1]; o.z += dl[2]; o.w += dl[3];
    *(f32x4*)(out + oi) = o;
}

extern "C" void kernel_launch(void* const* d_in, const int* in_sizes, int n_in,
                              void* d_out, int out_size, void* d_ws, size_t ws_size,
                              hipStream_t stream) {
    const float* x      = (const float*)d_in[0];
    const float* gamma  = (const float*)d_in[1];
    const float* beta   = (const float*)d_in[2];
    const float* bases  = (const float*)d_in[3];
    const float* slopes = (const float*)d_in[4];
    const float* oscale = (const float*)d_in[5];
    float* out = (float*)d_out;
    const int N = in_sizes[0] / D_MODEL;  // 16384

    // workspace layout
    char* w = (char*)d_ws;
    unsigned int* tminb = (unsigned int*)w; w += NUM_TILES * NBUCKET * 4;
    unsigned int* tmaxb = (unsigned int*)w; w += NUM_TILES * NBUCKET * 4;
    unsigned int* tmin  = (unsigned int*)w; w += 256;
    unsigned int* tmax  = (unsigned int*)w; w += 256;
    float* sgn = (float*)w;  w += D_MODEL * sizeof(float);
    int* tidx = (int*)w;     w += (size_t)N * sizeof(int);
    float* xns = (float*)w;  w += (size_t)N * D_SLICE * sizeof(float);

    kan_setup<<<(NUM_TILES * NBUCKET + 255) / 256, 256, 0, stream>>>(slopes, sgn, tminb, tmaxb);
    kan_main<<<N / 2, 256, 0, stream>>>(x, gamma, beta, sgn, out, xns, tidx, tminb, tmaxb);
    kan_reduce<<<1, 64, 0, stream>>>(tminb, tmaxb, tmin, tmax);
    kan_apply<<<(N * 8 + 255) / 256, 256, 0, stream>>>(xns, tidx, bases, slopes,
                                                       oscale, tmin, tmax, out, N);
}

// Round 12
// 68.451 us; speedup vs baseline: 1.0739x; 1.0739x over previous
//
#include <hip/hip_runtime.h>

#define D_MODEL 2048
#define NUM_TILES 64
#define D_SLICE 32
#define TILES_PER_CLUSTER 8
#define NUM_CLUSTERS 8
#define GRID_PTS 16
#define LN_EPS 1e-5f
#define NBUCKET 64

// native 4-float vector
typedef float f32x4 __attribute__((ext_vector_type(4)));

// order-preserving float<->uint map for atomic min/max
__device__ __forceinline__ unsigned int encF(float f) {
    unsigned int u = __float_as_uint(f);
    return (u & 0x80000000u) ? ~u : (u | 0x80000000u);
}
__device__ __forceinline__ float decF(unsigned int u) {
    unsigned int b = (u & 0x80000000u) ? (u ^ 0x80000000u) : ~u;
    return __uint_as_float(b);
}

// Kernel A: slope_sign per dim + init bucketed tile min/max (ws is poisoned).
__global__ void kan_setup(const float* __restrict__ slopes,
                          float* __restrict__ sgn,
                          unsigned int* __restrict__ tminb,
                          unsigned int* __restrict__ tmaxb) {
    int d = blockIdx.x * blockDim.x + threadIdx.x;  // 0..4095
    if (d < NUM_TILES * NBUCKET) { tminb[d] = 0xFFFFFFFFu; tmaxb[d] = 0u; }
    if (d < D_MODEL) {
        const float* p = slopes + (size_t)d * GRID_PTS;
        float s = 0.f;
#pragma unroll
        for (int k = 0; k < GRID_PTS; ++k) s += p[k];
        float m = s * (1.0f / GRID_PTS);
        sgn[d] = (m > 0.f) ? 1.f : ((m < 0.f) ? -1.f : 0.f);
    }
}

// Per-token body: R5/R6-verified wave-per-token logic. Wave-internal shuffles
// only; zero LDS, zero barriers; named scalars (no runtime-indexed register
// arrays -> no scratch).
__device__ __forceinline__ void process_token(
    f32x4 xc0, f32x4 xc1, f32x4 xc2, f32x4 xc3,
    f32x4 xc4, f32x4 xc5, f32x4 xc6, f32x4 xc7,
    int n, int l, int k,
    const float* __restrict__ x,
    const float* __restrict__ gamma,
    const float* __restrict__ beta,
    const float* __restrict__ sgn,
    float* __restrict__ out,
    float* __restrict__ xn_slice,
    int* __restrict__ tidx_out,
    unsigned int* __restrict__ tminb,
    unsigned int* __restrict__ tmaxb)
{
    const size_t rowb = (size_t)n * D_MODEL;

    // ---- out = x copy: plain cached stores, issued first ----
    float* orow = out + rowb + 4 * l;
    *(f32x4*)(orow)        = xc0;
    *(f32x4*)(orow + 256)  = xc1;
    *(f32x4*)(orow + 512)  = xc2;
    *(f32x4*)(orow + 768)  = xc3;
    *(f32x4*)(orow + 1024) = xc4;
    *(f32x4*)(orow + 1280) = xc5;
    *(f32x4*)(orow + 1536) = xc6;
    *(f32x4*)(orow + 1792) = xc7;

    // ---- fused sum + sumsq over 32 values, then 6-step wave butterfly ----
    float s = 0.f, q = 0.f;
#define ACC(V) { s += V.x + V.y + V.z + V.w; \
                 q += V.x*V.x + V.y*V.y + V.z*V.z + V.w*V.w; }
    ACC(xc0) ACC(xc1) ACC(xc2) ACC(xc3) ACC(xc4) ACC(xc5) ACC(xc6) ACC(xc7)
#undef ACC
#pragma unroll
    for (int off = 32; off > 0; off >>= 1) {
        s += __shfl_xor(s, off);
        q += __shfl_xor(q, off);
    }
    const float mu = s * (1.0f / D_MODEL);
    float var = q * (1.0f / D_MODEL) - mu * mu;
    var = fmaxf(var, 0.0f);
    const float rs = rsqrtf(var + LN_EPS);

    // ---- per-chunk: tile score, cluster sum, per-cluster winner ----
    const float* gp = gamma + 4 * l;
    const float* bp = beta + 4 * l;
    const float* sp = sgn + 4 * l;
    int cs0, cs1, cs2, cs3, cs4, cs5, cs6, cs7;
    int kw0, kw1, kw2, kw3, kw4, kw5, kw6, kw7;

#define CHUNK(c, XC, CS, KW)                                               \
    {                                                                      \
        f32x4 g  = *(const f32x4*)(gp + 256 * c);                          \
        f32x4 bb = *(const f32x4*)(bp + 256 * c);                          \
        f32x4 sg = *(const f32x4*)(sp + 256 * c);                          \
        float n0 = (XC.x - mu) * rs * g.x + bb.x;                          \
        float n1 = (XC.y - mu) * rs * g.y + bb.y;                          \
        float n2 = (XC.z - mu) * rs * g.z + bb.z;                          \
        float n3 = (XC.w - mu) * rs * g.w + bb.w;                          \
        int sc = ((n0 > 0.f) - (n0 < 0.f)) * (int)sg.x                     \
               + ((n1 > 0.f) - (n1 < 0.f)) * (int)sg.y                     \
               + ((n2 > 0.f) - (n2 < 0.f)) * (int)sg.z                     \
               + ((n3 > 0.f) - (n3 < 0.f)) * (int)sg.w;                    \
        sc += __shfl_xor(sc, 1);                                           \
        sc += __shfl_xor(sc, 2);                                           \
        sc += __shfl_xor(sc, 4);  /* tile score, replicated in group */    \
        int cm = sc;                                                       \
        cm += __shfl_xor(cm, 8);                                           \
        cm += __shfl_xor(cm, 16);                                          \
        cm += __shfl_xor(cm, 32); /* cluster sum, wave-uniform */          \
        CS = cm;                                                           \
        int key = ((sc + 64) << 3) | (7 - k);                              \
        key = max(key, __shfl_xor(key, 8));                                \
        key = max(key, __shfl_xor(key, 16));                               \
        key = max(key, __shfl_xor(key, 32)); /* wave-uniform */            \
        KW = 7 - (key & 7); /* winning k in cluster c (first-wins) */      \
    }
    CHUNK(0, xc0, cs0, kw0)
    CHUNK(1, xc1, cs1, kw1)
    CHUNK(2, xc2, cs2, kw2)
    CHUNK(3, xc3, cs3, kw3)
    CHUNK(4, xc4, cs4, kw4)
    CHUNK(5, xc5, cs5, kw5)
    CHUNK(6, xc6, cs6, kw6)
    CHUNK(7, xc7, cs7, kw7)
#undef CHUNK

    // ---- cluster argmax (first-wins), wave-uniform scalar chain ----
    int bc = 0, bv = cs0;
    if (cs1 > bv) { bv = cs1; bc = 1; }
    if (cs2 > bv) { bv = cs2; bc = 2; }
    if (cs3 > bv) { bv = cs3; bc = 3; }
    if (cs4 > bv) { bv = cs4; bc = 4; }
    if (cs5 > bv) { bv = cs5; bc = 5; }
    if (cs6 > bv) { bv = cs6; bc = 6; }
    if (cs7 > bv) { bv = cs7; bc = 7; }
    const int kwin = (bc == 0) ? kw0 : (bc == 1) ? kw1 : (bc == 2) ? kw2 :
                     (bc == 3) ? kw3 : (bc == 4) ? kw4 : (bc == 5) ? kw5 :
                     (bc == 6) ? kw6 : kw7;
    const int tile = bc * 8 + kwin;  // wave-uniform

    if (l == 0) tidx_out[n] = tile;

    // ---- chosen tile: 8 lanes of group kwin reload 16B from cache and
    //      recompute xn (avoids runtime register-select; x never mutated) ----
    if (k == kwin) {
        const int doff = 256 * bc + 4 * l;
        f32x4 xs = *(const f32x4*)(x + rowb + doff);
        f32x4 g  = *(const f32x4*)(gamma + doff);
        f32x4 bb = *(const f32x4*)(beta + doff);
        f32x4 xn4;
        xn4.x = (xs.x - mu) * rs * g.x + bb.x;
        xn4.y = (xs.y - mu) * rs * g.y + bb.y;
        xn4.z = (xs.z - mu) * rs * g.z + bb.z;
        xn4.w = (xs.w - mu) * rs * g.w + bb.w;

        *(f32x4*)(xn_slice + (size_t)n * D_SLICE + 4 * (l & 7)) = xn4;

        float mn = fminf(fminf(xn4.x, xn4.y), fminf(xn4.z, xn4.w));
        float mx = fmaxf(fmaxf(xn4.x, xn4.y), fmaxf(xn4.z, xn4.w));
        mn = fminf(mn, __shfl_xor(mn, 1));
        mn = fminf(mn, __shfl_xor(mn, 2));
        mn = fminf(mn, __shfl_xor(mn, 4));
        mx = fmaxf(mx, __shfl_xor(mx, 1));
        mx = fmaxf(mx, __shfl_xor(mx, 2));
        mx = fmaxf(mx, __shfl_xor(mx, 4));
        if ((l & 7) == 0) {
            int bkt = n & (NBUCKET - 1);
            atomicMin(&tminb[tile * NBUCKET + bkt], encF(mn));
            atomicMax(&tmaxb[tile * NBUCKET + bkt], encF(mx));
        }
    }
}

// Kernel B: one wave = TWO tokens, both rows' 16 loads issued up front
// (token 2's HBM latency hides under token 1's shuffle chain). Zero LDS,
// zero barriers (no vmcnt-drain points). 2048 blocks -> 32 waves/CU of work.
__launch_bounds__(256)
__global__ void kan_main(const float* __restrict__ x,
                         const float* __restrict__ gamma,
                         const float* __restrict__ beta,
                         const float* __restrict__ sgn,
                         float* __restrict__ out,
                         float* __restrict__ xn_slice,
                         int* __restrict__ tidx_out,
                         unsigned int* __restrict__ tminb,
                         unsigned int* __restrict__ tmaxb) {
    const int wid = threadIdx.x >> 6;
    const int l   = threadIdx.x & 63;
    const int k   = l >> 3;
    const int gw  = blockIdx.x * 4 + wid;  // global wave id, 0..8191
    const int nA  = gw * 2;
    const int nB  = nA + 1;

#define LOADX(P, nn) { const float* xr_ = x + (size_t)(nn) * D_MODEL + 4 * l; \
    P##0 = *(const f32x4*)(xr_);        P##1 = *(const f32x4*)(xr_ + 256);    \
    P##2 = *(const f32x4*)(xr_ + 512);  P##3 = *(const f32x4*)(xr_ + 768);    \
    P##4 = *(const f32x4*)(xr_ + 1024); P##5 = *(const f32x4*)(xr_ + 1280);   \
    P##6 = *(const f32x4*)(xr_ + 1536); P##7 = *(const f32x4*)(xr_ + 1792); }

    f32x4 a0, a1, a2, a3, a4, a5, a6, a7;
    f32x4 b0, b1, b2, b3, b4, b5, b6, b7;

    LOADX(a, nA)
    LOADX(b, nB)   // both rows in flight together (MLP = 16)
    process_token(a0, a1, a2, a3, a4, a5, a6, a7, nA, l, k,
                  x, gamma, beta, sgn, out, xn_slice, tidx_out, tminb, tmaxb);
    process_token(b0, b1, b2, b3, b4, b5, b6, b7, nB, l, k,
                  x, gamma, beta, sgn, out, xn_slice, tidx_out, tminb, tmaxb);
#undef LOADX
}

// Kernel C: 8 threads per token. First each token's threads reduce its
// tile's 64 min/max buckets from L2 (8 buckets/thread + 3-step shuffle —
// replaces the kan_reduce launch), then spline delta + float4 RMW on out.
__global__ void kan_apply(const float* __restrict__ xn_slice,
                          const int* __restrict__ tidx,
                          const float* __restrict__ bases,
                          const float* __restrict__ slopes,
                          const float* __restrict__ oscale,
                          const unsigned int* __restrict__ tminb,
                          const unsigned int* __restrict__ tmaxb,
                          float* __restrict__ out, int N) {
    int g = blockIdx.x * blockDim.x + threadIdx.x;
    if (g >= N * 8) return;
    int n = g >> 3;
    int qd = g & 7;  // quad of 4 dims: j = 4*qd..4*qd+3
    int t = tidx[n];

    // ---- bucket reduce: thread qd covers buckets 8*qd..8*qd+7 ----
    unsigned int mnu = 0xFFFFFFFFu, mxu = 0u;
    const unsigned int* bmn = tminb + t * NBUCKET + qd * 8;
    const unsigned int* bmx = tmaxb + t * NBUCKET + qd * 8;
#pragma unroll
    for (int i = 0; i < 8; ++i) {
        mnu = min(mnu, bmn[i]);
        mxu = max(mxu, bmx[i]);
    }
    // 8-lane group shuffle reduce (lanes of one token are an aligned group)
    mnu = min(mnu, (unsigned int)__shfl_xor((int)mnu, 1));
    mnu = min(mnu, (unsigned int)__shfl_xor((int)mnu, 2));
    mnu = min(mnu, (unsigned int)__shfl_xor((int)mnu, 4));
    mxu = max(mxu, (unsigned int)__shfl_xor((int)mxu, 1));
    mxu = max(mxu, (unsigned int)__shfl_xor((int)mxu, 2));
    mxu = max(mxu, (unsigned int)__shfl_xor((int)mxu, 4));
    float mn = decF(mnu);
    float mx = decF(mxu);

    f32x4 xn4 = *(const f32x4*)(xn_slice + (size_t)n * D_SLICE + qd * 4);
    float inv = 1.0f / (mx - mn + 1e-8f);
    float osc = oscale[t];

    float dl[4];
    float xnv[4] = {xn4.x, xn4.y, xn4.z, xn4.w};
#pragma unroll
    for (int e = 0; e < 4; ++e) {
        float u = (xnv[e] - mn) * inv;
        u = fminf(fmaxf(u, 0.0f), 1.0f - 1e-6f);
        int gi = (int)(u * (float)GRID_PTS);
        gi = min(max(gi, 0), GRID_PTS - 1);
        int j = qd * 4 + e;
        int off = (t * D_SLICE + j) * GRID_PTS + gi;
        float xl = (u - (float)gi * (1.0f / GRID_PTS)) * (float)GRID_PTS;
        dl[e] = (bases[off] + slopes[off] * xl) * osc;
    }
    size_t oi = (size_t)n * D_MODEL + t * D_SLICE + qd * 4;
    f32x4 o = *(f32x4*)(out + oi);
    o.x += dl[0]; o.y += dl[1]; o.z += dl[2]; o.w += dl[3];
    *(f32x4*)(out + oi) = o;
}

extern "C" void kernel_launch(void* const* d_in, const int* in_sizes, int n_in,
                              void* d_out, int out_size, void* d_ws, size_t ws_size,
                              hipStream_t stream) {
    const float* x      = (const float*)d_in[0];
    const float* gamma  = (const float*)d_in[1];
    const float* beta   = (const float*)d_in[2];
    const float* bases  = (const float*)d_in[3];
    const float* slopes = (const float*)d_in[4];
    const float* oscale = (const float*)d_in[5];
    float* out = (float*)d_out;
    const int N = in_sizes[0] / D_MODEL;  // 16384

    // workspace layout
    char* w = (char*)d_ws;
    unsigned int* tminb = (unsigned int*)w; w += NUM_TILES * NBUCKET * 4;
    unsigned int* tmaxb = (unsigned int*)w; w += NUM_TILES * NBUCKET * 4;
    float* sgn = (float*)w;  w += D_MODEL * sizeof(float);
    int* tidx = (int*)w;     w += (size_t)N * sizeof(int);
    float* xns = (float*)w;  w += (size_t)N * D_SLICE * sizeof(float);

    kan_setup<<<(NUM_TILES * NBUCKET + 255) / 256, 256, 0, stream>>>(slopes, sgn, tminb, tmaxb);
    kan_main<<<N / 8, 256, 0, stream>>>(x, gamma, beta, sgn, out, xns, tidx, tminb, tmaxb);
    kan_apply<<<(N * 8 + 255) / 256, 256, 0, stream>>>(xns, tidx, bases, slopes,
                                                       oscale, tminb, tmaxb, out, N);
}

// Round 13
// 60.144 us; speedup vs baseline: 1.2223x; 1.1381x over previous
//
#include <hip/hip_runtime.h>

#define D_MODEL 2048
#define NUM_TILES 64
#define D_SLICE 32
#define TILES_PER_CLUSTER 8
#define NUM_CLUSTERS 8
#define GRID_PTS 16
#define LN_EPS 1e-5f
#define NBUCKET 64

// native 4-float vector (works with __builtin_nontemporal_*)
typedef float f32x4 __attribute__((ext_vector_type(4)));

// order-preserving float<->uint map for atomic min/max
__device__ __forceinline__ unsigned int encF(float f) {
    unsigned int u = __float_as_uint(f);
    return (u & 0x80000000u) ? ~u : (u | 0x80000000u);
}
__device__ __forceinline__ float decF(unsigned int u) {
    unsigned int b = (u & 0x80000000u) ? (u ^ 0x80000000u) : ~u;
    return __uint_as_float(b);
}

// Kernel A: slope_sign per dim + init bucketed tile min/max (ws is poisoned).
__global__ void kan_setup(const float* __restrict__ slopes,
                          float* __restrict__ sgn,
                          unsigned int* __restrict__ tminb,
                          unsigned int* __restrict__ tmaxb) {
    int d = blockIdx.x * blockDim.x + threadIdx.x;  // 0..4095
    if (d < NUM_TILES * NBUCKET) { tminb[d] = 0xFFFFFFFFu; tmaxb[d] = 0u; }
    if (d < D_MODEL) {
        const float* p = slopes + (size_t)d * GRID_PTS;
        float s = 0.f;
#pragma unroll
        for (int k = 0; k < GRID_PTS; ++k) s += p[k];
        float m = s * (1.0f / GRID_PTS);
        sgn[d] = (m > 0.f) ? 1.f : ((m < 0.f) ? -1.f : 0.f);
    }
}

// Kernel B: one block per token (best-measured configuration, R4 verbatim).
// Fused one-pass mean/var (E[x^2]-mu^2), early nontemporal out=x copy,
// hoisted weight loads, parallel cluster sums + serial argmax, bucketed
// low-contention atomics.
__launch_bounds__(256)
__global__ void kan_main(const float* __restrict__ x,
                         const float* __restrict__ gamma,
                         const float* __restrict__ beta,
                         const float* __restrict__ sgn,
                         float* __restrict__ out,
                         float* __restrict__ xn_slice,
                         int* __restrict__ tidx_out,
                         unsigned int* __restrict__ tminb,
                         unsigned int* __restrict__ tmaxb) {
    const int n = blockIdx.x;
    const int tid = threadIdx.x;
    const size_t base = (size_t)n * D_MODEL + (size_t)tid * 8;

    // load 8 contiguous dims (all within tile tid>>2)
    f32x4 a = *(const f32x4*)(x + base);
    f32x4 b = *(const f32x4*)(x + base + 4);

    // ---- out = x copy: issue immediately, nontemporal ----
    __builtin_nontemporal_store(a, (f32x4*)(out + base));
    __builtin_nontemporal_store(b, (f32x4*)(out + base + 4));

    // ---- hoist weight loads (in flight during the reduction) ----
    f32x4 g0 = *(const f32x4*)(gamma + tid * 8);
    f32x4 g1 = *(const f32x4*)(gamma + tid * 8 + 4);
    f32x4 b0 = *(const f32x4*)(beta + tid * 8);
    f32x4 b1 = *(const f32x4*)(beta + tid * 8 + 4);
    f32x4 sg0 = *(const f32x4*)(sgn + tid * 8);
    f32x4 sg1 = *(const f32x4*)(sgn + tid * 8 + 4);

    float xv[8] = {a.x, a.y, a.z, a.w, b.x, b.y, b.z, b.w};

    __shared__ float2 red[4];
    __shared__ int ts[NUM_TILES];
    __shared__ int cs[NUM_CLUSTERS];
    __shared__ int chosen;

    // ---- fused sum + sumsq, single butterfly + single barrier ----
    float s = 0.f, q = 0.f;
#pragma unroll
    for (int k = 0; k < 8; ++k) { s += xv[k]; q += xv[k] * xv[k]; }
#pragma unroll
    for (int off = 32; off > 0; off >>= 1) {
        s += __shfl_xor(s, off);
        q += __shfl_xor(q, off);
    }
    if ((tid & 63) == 0) red[tid >> 6] = make_float2(s, q);
    __syncthreads();
    float S = red[0].x + red[1].x + red[2].x + red[3].x;
    float Q = red[0].y + red[1].y + red[2].y + red[3].y;
    const float mu = S * (1.0f / D_MODEL);
    float var = Q * (1.0f / D_MODEL) - mu * mu;
    var = fmaxf(var, 0.0f);
    const float rs = rsqrtf(var + LN_EPS);

    // ---- normalized values + integer sign score ----
    float gv[8] = {g0.x, g0.y, g0.z, g0.w, g1.x, g1.y, g1.z, g1.w};
    float bv[8] = {b0.x, b0.y, b0.z, b0.w, b1.x, b1.y, b1.z, b1.w};
    float sv[8] = {sg0.x, sg0.y, sg0.z, sg0.w, sg1.x, sg1.y, sg1.z, sg1.w};

    float xn[8];
    int sc = 0;
#pragma unroll
    for (int k = 0; k < 8; ++k) {
        xn[k] = (xv[k] - mu) * rs * gv[k] + bv[k];
        int s1 = (xn[k] > 0.f) ? 1 : ((xn[k] < 0.f) ? -1 : 0);
        sc += s1 * (int)sv[k];
    }
    sc += __shfl_xor(sc, 1);
    sc += __shfl_xor(sc, 2);
    if ((tid & 3) == 0) ts[tid >> 2] = sc;
    __syncthreads();

    // ---- argmax: 8 threads sum clusters in parallel, thread 0 compares ----
    if (tid < NUM_CLUSTERS) {
        int c = 0;
#pragma unroll
        for (int t = 0; t < TILES_PER_CLUSTER; ++t) c += ts[tid * TILES_PER_CLUSTER + t];
        cs[tid] = c;
    }
    __syncthreads();
    if (tid == 0) {
        int bc = 0, bv_ = -2147483647;
#pragma unroll
        for (int c = 0; c < NUM_CLUSTERS; ++c)
            if (cs[c] > bv_) { bv_ = cs[c]; bc = c; }
        int t0 = bc * TILES_PER_CLUSTER;
        int bt = t0, btv = ts[t0];
#pragma unroll
        for (int t = 1; t < TILES_PER_CLUSTER; ++t)
            if (ts[t0 + t] > btv) { btv = ts[t0 + t]; bt = t0 + t; }
        chosen = bt;
        tidx_out[n] = bt;
    }
    __syncthreads();
    const int tile = chosen;

    // ---- stash xn slice of chosen tile (4 threads, 128B contiguous) ----
    if ((tid >> 2) == tile) {
        float* qp = xn_slice + (size_t)n * D_SLICE + (tid & 3) * 8;
        *(f32x4*)(qp) = f32x4{xn[0], xn[1], xn[2], xn[3]};
        *(f32x4*)(qp + 4) = f32x4{xn[4], xn[5], xn[6], xn[7]};
    }

    // ---- chosen-tile min/max -> bucketed atomics (contention / 64) ----
    float mn8 = xn[0], mx8 = xn[0];
#pragma unroll
    for (int k = 1; k < 8; ++k) { mn8 = fminf(mn8, xn[k]); mx8 = fmaxf(mx8, xn[k]); }
    mn8 = fminf(mn8, __shfl_xor(mn8, 1));
    mn8 = fminf(mn8, __shfl_xor(mn8, 2));
    mx8 = fmaxf(mx8, __shfl_xor(mx8, 1));
    mx8 = fmaxf(mx8, __shfl_xor(mx8, 2));
    if (tid == tile * 4) {
        int bkt = blockIdx.x & (NBUCKET - 1);
        atomicMin(&tminb[tile * NBUCKET + bkt], encF(mn8));
        atomicMax(&tmaxb[tile * NBUCKET + bkt], encF(mx8));
    }
}

// Kernel C: 8 threads per token. Each token's threads reduce its tile's 64
// min/max buckets from L2 (8 buckets/thread + 3-step shuffle — replaces the
// kan_reduce launch), then spline delta + float4 RMW on out. (R11-verified.)
__global__ void kan_apply(const float* __restrict__ xn_slice,
                          const int* __restrict__ tidx,
                          const float* __restrict__ bases,
                          const float* __restrict__ slopes,
                          const float* __restrict__ oscale,
                          const unsigned int* __restrict__ tminb,
                          const unsigned int* __restrict__ tmaxb,
                          float* __restrict__ out, int N) {
    int g = blockIdx.x * blockDim.x + threadIdx.x;
    if (g >= N * 8) return;
    int n = g >> 3;
    int qd = g & 7;  // quad of 4 dims: j = 4*qd..4*qd+3
    int t = tidx[n];

    // ---- bucket reduce: thread qd covers buckets 8*qd..8*qd+7 ----
    unsigned int mnu = 0xFFFFFFFFu, mxu = 0u;
    const unsigned int* bmn = tminb + t * NBUCKET + qd * 8;
    const unsigned int* bmx = tmaxb + t * NBUCKET + qd * 8;
#pragma unroll
    for (int i = 0; i < 8; ++i) {
        mnu = min(mnu, bmn[i]);
        mxu = max(mxu, bmx[i]);
    }
    // 8-lane group shuffle reduce (token's threads are an aligned 8-group)
    mnu = min(mnu, (unsigned int)__shfl_xor((int)mnu, 1));
    mnu = min(mnu, (unsigned int)__shfl_xor((int)mnu, 2));
    mnu = min(mnu, (unsigned int)__shfl_xor((int)mnu, 4));
    mxu = max(mxu, (unsigned int)__shfl_xor((int)mxu, 1));
    mxu = max(mxu, (unsigned int)__shfl_xor((int)mxu, 2));
    mxu = max(mxu, (unsigned int)__shfl_xor((int)mxu, 4));
    float mn = decF(mnu);
    float mx = decF(mxu);

    f32x4 xn4 = *(const f32x4*)(xn_slice + (size_t)n * D_SLICE + qd * 4);
    float inv = 1.0f / (mx - mn + 1e-8f);
    float osc = oscale[t];

    float dl[4];
    float xnv[4] = {xn4.x, xn4.y, xn4.z, xn4.w};
#pragma unroll
    for (int e = 0; e < 4; ++e) {
        float u = (xnv[e] - mn) * inv;
        u = fminf(fmaxf(u, 0.0f), 1.0f - 1e-6f);
        int gi = (int)(u * (float)GRID_PTS);
        gi = min(max(gi, 0), GRID_PTS - 1);
        int j = qd * 4 + e;
        int off = (t * D_SLICE + j) * GRID_PTS + gi;
        float xl = (u - (float)gi * (1.0f / GRID_PTS)) * (float)GRID_PTS;
        dl[e] = (bases[off] + slopes[off] * xl) * osc;
    }
    size_t oi = (size_t)n * D_MODEL + t * D_SLICE + qd * 4;
    f32x4 o = *(f32x4*)(out + oi);
    o.x += dl[0]; o.y += dl[1]; o.z += dl[2]; o.w += dl[3];
    *(f32x4*)(out + oi) = o;
}

extern "C" void kernel_launch(void* const* d_in, const int* in_sizes, int n_in,
                              void* d_out, int out_size, void* d_ws, size_t ws_size,
                              hipStream_t stream) {
    const float* x      = (const float*)d_in[0];
    const float* gamma  = (const float*)d_in[1];
    const float* beta   = (const float*)d_in[2];
    const float* bases  = (const float*)d_in[3];
    const float* slopes = (const float*)d_in[4];
    const float* oscale = (const float*)d_in[5];
    float* out = (float*)d_out;
    const int N = in_sizes[0] / D_MODEL;  // 16384

    // workspace layout
    char* w = (char*)d_ws;
    unsigned int* tminb = (unsigned int*)w; w += NUM_TILES * NBUCKET * 4;
    unsigned int* tmaxb = (unsigned int*)w; w += NUM_TILES * NBUCKET * 4;
    float* sgn = (float*)w;  w += D_MODEL * sizeof(float);
    int* tidx = (int*)w;     w += (size_t)N * sizeof(int);
    float* xns = (float*)w;  w += (size_t)N * D_SLICE * sizeof(float);

    kan_setup<<<(NUM_TILES * NBUCKET + 255) / 256, 256, 0, stream>>>(slopes, sgn, tminb, tmaxb);
    kan_main<<<N, 256, 0, stream>>>(x, gamma, beta, sgn, out, xns, tidx, tminb, tmaxb);
    kan_apply<<<(N * 8 + 255) / 256, 256, 0, stream>>>(xns, tidx, bases, slopes,
                                                       oscale, tminb, tmaxb, out, N);
}